// Round 5
// baseline (764.479 us; speedup 1.0000x reference)
//
#include <hip/hip_runtime.h>
#include <hip/hip_bf16.h>
#include <math.h>

#define B_DIM 65536
#define N_DIM 1024
#define DT_C 0.01f
#define NS_SCALE 0.01f   // NOISE_STD * sqrt(DT) = 0.1 * 0.1

typedef __attribute__((ext_vector_type(8))) short bf16x8;
typedef __attribute__((ext_vector_type(4))) float f32x4;

__device__ __forceinline__ unsigned short f2bf(float f) {
    union { float f; unsigned int u; } a;
    a.f = f;
    unsigned int r = a.u + 0x7fffu + ((a.u >> 16) & 1u);
    return (unsigned short)(r >> 16);
}
__device__ __forceinline__ float bf2f(unsigned short u) {
    union { unsigned int u; float f; } a;
    a.u = ((unsigned int)u) << 16;
    return a.f;
}
__device__ __forceinline__ void gload_lds16(const void* g, void* l) {
    __builtin_amdgcn_global_load_lds(
        (const __attribute__((address_space(1))) void*)g,
        (__attribute__((address_space(3))) void*)l, 16, 0, 0);
}

// K (fp32, row-major N x N) -> bf16
__global__ void k_convK(const float* __restrict__ K, unsigned short* __restrict__ Kbf) {
    int i = blockIdx.x * blockDim.x + threadIdx.x;
    float4 v = reinterpret_cast<const float4*>(K)[i];
    ushort4 o;
    o.x = f2bf(v.x); o.y = f2bf(v.y); o.z = f2bf(v.z); o.w = f2bf(v.w);
    reinterpret_cast<ushort4*>(Kbf)[i] = o;
}

// Precompute sin/cos(theta) for rows [rbase, rbase+R) into sc (bf16).
// Tile-ready layout: group g=row/64 occupies rows [g*128, g*128+128):
//   first 64 = sin rows, next 64 = cos rows.
__global__ __launch_bounds__(256)
void k_prep(const float* __restrict__ theta, unsigned short* __restrict__ sc, int rbase) {
    const int i   = blockIdx.x * 256 + threadIdx.x;
    const int row = i >> 7;            // row within chunk
    const int kk  = (i & 127) * 8;
    const float* tp = theta + (size_t)(rbase + row) * N_DIM + kk;
    float4 a = *reinterpret_cast<const float4*>(tp);
    float4 b = *reinterpret_cast<const float4*>(tp + 4);
    float in[8] = {a.x, a.y, a.z, a.w, b.x, b.y, b.z, b.w};
    bf16x8 sv, cv;
#pragma unroll
    for (int e = 0; e < 8; ++e) {
        float s, c;
        __sincosf(in[e], &s, &c);
        sv[e] = (short)f2bf(s);
        cv[e] = (short)f2bf(c);
    }
    const int srow = (row >> 6) * 128 + (row & 63);
    *reinterpret_cast<bf16x8*>(sc + (size_t)srow * N_DIM + kk)        = sv;
    *reinterpret_cast<bf16x8*>(sc + (size_t)(srow + 64) * N_DIM + kk) = cv;
}

// m97-structure GEMM: 128x128 tile (64 batch rows x [s;c] x 128 cols), BK=64,
// 256 threads / 4 waves (set-split: w0,w1 -> Ks; w2,w3 -> Kc), single 32KB LDS
// buffer, global_load_lds w16 staging, 2 barriers per K-step.
__global__ __launch_bounds__(256, 4)
void k_gemm(const unsigned short* __restrict__ sc,
            const float* __restrict__ theta,
            const float* __restrict__ noise,
            const float* __restrict__ omega,
            const unsigned short* __restrict__ Kbf,
            float* __restrict__ out, int rbase) {
    // GEMM: sA [g(8)][row(128)][8] @0 (8192 ushorts), sB same @8192. 32KB.
    // Epilogue: eS [64][128] @0, eC @8192, XOR-swizzled (cc ^= ((rr>>2)&3)<<4).
    __shared__ unsigned short smem[16384];

    const int tid  = threadIdx.x;
    const int lane = tid & 63;
    const int w    = tid >> 6;      // 0..3
    const int wsel = w >> 1;        // 0 = sin-set (Ks), 1 = cos-set (Kc)
    const int wn   = w & 1;         // col half

    // XCD swizzle: keep the 8 col-tiles of one row-panel on one XCD
    const int nwg     = gridDim.x;          // multiple of 8
    const int cpx     = nwg >> 3;
    const int logical = (blockIdx.x & 7) * cpx + (blockIdx.x >> 3);
    const int mt      = logical >> 3;
    const int nt      = logical & 7;

    f32x4 acc[4][4];
#pragma unroll
    for (int mi = 0; mi < 4; ++mi)
#pragma unroll
        for (int ni = 0; ni < 4; ++ni)
            acc[mi][ni] = (f32x4){0.f, 0.f, 0.f, 0.f};

    const int lr = lane & 15;
    const int kq = lane >> 4;

    for (int kt = 0; kt < 16; ++kt) {
        __syncthreads();   // everyone done reading buffer from previous step
#pragma unroll
        for (int j = 0; j < 4; ++j) {
            const int s    = w * 4 + j;
            const int g    = s & 7;
            const int half = s >> 3;
            // A: sc rows [mt*128 .. +128)
            const unsigned short* srcA =
                sc + (size_t)(mt * 128 + half * 64 + lane) * N_DIM + kt * 64 + g * 8;
            gload_lds16(srcA, &smem[(g * 128 + half * 64) * 8]);
            // B: K cols [nt*128 .. +128)
            const unsigned short* srcB =
                Kbf + (size_t)(nt * 128 + half * 64 + lane) * N_DIM + kt * 64 + g * 8;
            gload_lds16(srcB, &smem[8192 + (g * 128 + half * 64) * 8]);
        }
        __syncthreads();   // staging complete (vmcnt drained by syncthreads)

#pragma unroll
        for (int kk = 0; kk < 2; ++kk) {
            const int g = kk * 4 + kq;
            bf16x8 aF[4], bF[4];
#pragma unroll
            for (int mi = 0; mi < 4; ++mi)
                aF[mi] = *reinterpret_cast<const bf16x8*>(
                    &smem[(g * 128 + wsel * 64 + mi * 16 + lr) * 8]);
#pragma unroll
            for (int ni = 0; ni < 4; ++ni)
                bF[ni] = *reinterpret_cast<const bf16x8*>(
                    &smem[8192 + (g * 128 + wn * 64 + ni * 16 + lr) * 8]);
#pragma unroll
            for (int mi = 0; mi < 4; ++mi)
#pragma unroll
                for (int ni = 0; ni < 4; ++ni)
                    acc[mi][ni] = __builtin_amdgcn_mfma_f32_16x16x32_bf16(
                        aF[mi], bF[ni], acc[mi][ni], 0, 0, 0);
        }
    }

    __syncthreads();  // last compute's ds_reads done before overwriting smem

    // ---- exchange Ks/Kc via LDS (bf16, XOR-swizzled; conflict-free) ----
    {
        const int base = wsel * 8192;
#pragma unroll
        for (int mi = 0; mi < 4; ++mi)
#pragma unroll
            for (int ni = 0; ni < 4; ++ni) {
                const int cc = wn * 64 + ni * 16 + lr;
#pragma unroll
                for (int v = 0; v < 4; ++v) {
                    const int rr = mi * 16 + (lane >> 4) * 4 + v;
                    smem[base + rr * 128 + (cc ^ (((rr >> 2) & 3) << 4))] =
                        f2bf(acc[mi][ni][v]);
                }
            }
    }
    __syncthreads();

    // ---- fused elementwise: out = th + (om + c*Ks - s*Kc)*DT + nz*NS ----
    {
        const int c4   = (tid & 31) * 4;
        const int gcol = nt * 128 + c4;
        float4 om = *reinterpret_cast<const float4*>(&omega[gcol]);
#pragma unroll
        for (int p = 0; p < 8; ++p) {
            const int rr  = p * 8 + (tid >> 5);
            const int key = ((rr >> 2) & 3) << 4;
            ushort4 us = *reinterpret_cast<ushort4*>(&smem[rr * 128 + (c4 ^ key)]);
            ushort4 uc = *reinterpret_cast<ushort4*>(&smem[8192 + rr * 128 + (c4 ^ key)]);
            const size_t gidx = (size_t)(rbase + mt * 64 + rr) * N_DIM + gcol;
            float4 th = *reinterpret_cast<const float4*>(&theta[gidx]);
            float4 nz = *reinterpret_cast<const float4*>(&noise[gidx]);
            float4 o;
            {
                float sn, cn; __sincosf(th.x, &sn, &cn);
                o.x = th.x + (om.x + cn * bf2f(us.x) - sn * bf2f(uc.x)) * DT_C + nz.x * NS_SCALE;
            }
            {
                float sn, cn; __sincosf(th.y, &sn, &cn);
                o.y = th.y + (om.y + cn * bf2f(us.y) - sn * bf2f(uc.y)) * DT_C + nz.y * NS_SCALE;
            }
            {
                float sn, cn; __sincosf(th.z, &sn, &cn);
                o.z = th.z + (om.z + cn * bf2f(us.z) - sn * bf2f(uc.z)) * DT_C + nz.z * NS_SCALE;
            }
            {
                float sn, cn; __sincosf(th.w, &sn, &cn);
                o.w = th.w + (om.w + cn * bf2f(us.w) - sn * bf2f(uc.w)) * DT_C + nz.w * NS_SCALE;
            }
            *reinterpret_cast<float4*>(&out[gidx]) = o;
        }
    }
}

// ---------------- fallback (R2 kernel, ws too small) ----------------
#define FB_BM 64
#define FB_BN 256
__global__ __launch_bounds__(512, 4)
void k_fused_fb(const float* __restrict__ theta,
                const float* __restrict__ noise,
                const float* __restrict__ omega,
                const unsigned short* __restrict__ Kbf,
                float* __restrict__ out) {
    __shared__ unsigned short sA[2][2][4][FB_BM][8];
    __shared__ unsigned short sB[2][4][FB_BN][8];

    const int tid  = threadIdx.x;
    const int lane = tid & 63;
    const int w    = tid >> 6;
    const int wm   = w >> 2;
    const int wn   = w & 3;

    const int nwg     = gridDim.x;
    const int cpx     = nwg >> 3;
    const int logical = (blockIdx.x & 7) * cpx + (blockIdx.x >> 3);
    const int mt      = logical >> 2;
    const int nt      = logical & 3;
    const int row0    = mt * FB_BM;
    const int col0    = nt * FB_BN;

    const int q = tid >> 7;
    const int r = (tid >> 1) & 63;
    const int h = tid & 1;
    const int rb  = (w & 3) * 64;
    const int it0 = (w >> 2) * 2;

    f32x4 accS[2][4], accC[2][4];
#pragma unroll
    for (int mi = 0; mi < 2; ++mi)
#pragma unroll
        for (int ni = 0; ni < 4; ++ni) {
            accS[mi][ni] = (f32x4){0.f, 0.f, 0.f, 0.f};
            accC[mi][ni] = (f32x4){0.f, 0.f, 0.f, 0.f};
        }

    auto stage = [&](int buf, int kt) {
#pragma unroll
        for (int j = 0; j < 2; ++j) {
            const int it = it0 + j;
            const unsigned short* src =
                Kbf + (size_t)(col0 + rb + lane) * N_DIM + kt * 32 + it * 8;
            gload_lds16(src, &sB[buf][it][rb][0]);
        }
        const float* gp = theta + (size_t)(row0 + r) * N_DIM + kt * 32 + q * 8 + h * 4;
        float4 v = *reinterpret_cast<const float4*>(gp);
        ushort4 sv, cv;
        {
            float s0, c0, s1, c1, s2, c2, s3, c3;
            __sincosf(v.x, &s0, &c0);
            __sincosf(v.y, &s1, &c1);
            __sincosf(v.z, &s2, &c2);
            __sincosf(v.w, &s3, &c3);
            sv.x = f2bf(s0); sv.y = f2bf(s1); sv.z = f2bf(s2); sv.w = f2bf(s3);
            cv.x = f2bf(c0); cv.y = f2bf(c1); cv.z = f2bf(c2); cv.w = f2bf(c3);
        }
        *reinterpret_cast<ushort4*>(&sA[buf][0][q][r][h * 4]) = sv;
        *reinterpret_cast<ushort4*>(&sA[buf][1][q][r][h * 4]) = cv;
    };

    auto compute = [&](int buf) {
        const int kq2 = lane >> 4;
        const int lr2 = lane & 15;
        bf16x8 aS[2], aC[2];
#pragma unroll
        for (int mi = 0; mi < 2; ++mi) {
            aS[mi] = *reinterpret_cast<const bf16x8*>(&sA[buf][0][kq2][wm * 32 + mi * 16 + lr2][0]);
            aC[mi] = *reinterpret_cast<const bf16x8*>(&sA[buf][1][kq2][wm * 32 + mi * 16 + lr2][0]);
        }
#pragma unroll
        for (int ni = 0; ni < 4; ++ni) {
            bf16x8 bF = *reinterpret_cast<const bf16x8*>(&sB[buf][kq2][wn * 64 + ni * 16 + lr2][0]);
#pragma unroll
            for (int mi = 0; mi < 2; ++mi) {
                accS[mi][ni] = __builtin_amdgcn_mfma_f32_16x16x32_bf16(aS[mi], bF, accS[mi][ni], 0, 0, 0);
                accC[mi][ni] = __builtin_amdgcn_mfma_f32_16x16x32_bf16(aC[mi], bF, accC[mi][ni], 0, 0, 0);
            }
        }
    };

    stage(0, 0);
    __syncthreads();
    int cur = 0;
    for (int kt = 0; kt < 32; ++kt) {
        if (kt + 1 < 32) stage(cur ^ 1, kt + 1);
        compute(cur);
        __syncthreads();
        cur ^= 1;
    }

#pragma unroll
    for (int mi = 0; mi < 2; ++mi) {
#pragma unroll
        for (int ni = 0; ni < 4; ++ni) {
            const int colg = col0 + wn * 64 + ni * 16 + (lane & 15);
            const float om = omega[colg];
#pragma unroll
            for (int v = 0; v < 4; ++v) {
                const int rowg = row0 + wm * 32 + mi * 16 + (lane >> 4) * 4 + v;
                const size_t idx = (size_t)rowg * N_DIM + colg;
                const float th = theta[idx];
                float sn, cn;
                __sincosf(th, &sn, &cn);
                const float coup = cn * accS[mi][ni][v] - sn * accC[mi][ni][v];
                out[idx] = th + (om + coup) * DT_C + noise[idx] * NS_SCALE;
            }
        }
    }
}

extern "C" void kernel_launch(void* const* d_in, const int* in_sizes, int n_in,
                              void* d_out, int out_size, void* d_ws, size_t ws_size,
                              hipStream_t stream) {
    const float* theta = (const float*)d_in[0];
    const float* noise = (const float*)d_in[1];
    const float* omega = (const float*)d_in[2];
    const float* K     = (const float*)d_in[3];
    float* out = (float*)d_out;

    unsigned short* Kbf = (unsigned short*)d_ws;   // 2 MB @ offset 0
    k_convK<<<(N_DIM * N_DIM) / (256 * 4), 256, 0, stream>>>(K, Kbf);

    // Choose chunk R (rows): sc chunk needs R*4096 bytes after a 4MB reserve.
    size_t avail = ws_size > (size_t)(4 << 20) ? ws_size - (size_t)(4 << 20) : 0;
    int R = 0;
    for (int cand = 65536; cand >= 1024; cand >>= 1)
        if ((size_t)cand * 4096 <= avail) { R = cand; break; }

    if (R > 0) {
        unsigned short* sc = (unsigned short*)((char*)d_ws + (4 << 20));
        const int nch = B_DIM / R;
        for (int ch = 0; ch < nch; ++ch) {
            const int rbase = ch * R;
            k_prep<<<R / 2, 256, 0, stream>>>(theta, sc, rbase);
            k_gemm<<<(R / 64) * 8, 256, 0, stream>>>(sc, theta, noise, omega, Kbf, out, rbase);
        }
    } else {
        k_fused_fb<<<(B_DIM / FB_BM) * (N_DIM / FB_BN), 512, 0, stream>>>(
            theta, noise, omega, Kbf, out);
    }
}

// Round 6
// 647.544 us; speedup vs baseline: 1.1806x; 1.1806x over previous
//
#include <hip/hip_runtime.h>
#include <hip/hip_bf16.h>
#include <math.h>

#define B_DIM 65536
#define N_DIM 1024
#define DT_C 0.01f
#define NS_SCALE 0.01f   // NOISE_STD * sqrt(DT) = 0.1 * 0.1

typedef __attribute__((ext_vector_type(8))) short bf16x8;
typedef __attribute__((ext_vector_type(4))) float f32x4;

__device__ __forceinline__ unsigned short f2bf(float f) {
    union { float f; unsigned int u; } a;
    a.f = f;
    unsigned int r = a.u + 0x7fffu + ((a.u >> 16) & 1u);
    return (unsigned short)(r >> 16);
}
__device__ __forceinline__ float bf2f(unsigned short u) {
    union { unsigned int u; float f; } a;
    a.u = ((unsigned int)u) << 16;
    return a.f;
}
__device__ __forceinline__ void gload_lds16(const void* g, void* l) {
    __builtin_amdgcn_global_load_lds(
        (const __attribute__((address_space(1))) void*)g,
        (__attribute__((address_space(3))) void*)l, 16, 0, 0);
}

// K (fp32, row-major N x N) -> bf16
__global__ void k_convK(const float* __restrict__ K, unsigned short* __restrict__ Kbf) {
    int i = blockIdx.x * blockDim.x + threadIdx.x;
    float4 v = reinterpret_cast<const float4*>(K)[i];
    ushort4 o;
    o.x = f2bf(v.x); o.y = f2bf(v.y); o.z = f2bf(v.z); o.w = f2bf(v.w);
    reinterpret_cast<ushort4*>(Kbf)[i] = o;
}

// Precompute sin/cos(theta) for rows [rbase, rbase+R) into sc (bf16).
// Group g=row/64 occupies sc rows [g*128, g*128+128): 64 sin rows, 64 cos rows.
__global__ __launch_bounds__(256)
void k_prep(const float* __restrict__ theta, unsigned short* __restrict__ sc, int rbase) {
    const int i   = blockIdx.x * 256 + threadIdx.x;
    const int row = i >> 7;            // row within chunk
    const int kk  = (i & 127) * 8;
    const float* tp = theta + (size_t)(rbase + row) * N_DIM + kk;
    float4 a = *reinterpret_cast<const float4*>(tp);
    float4 b = *reinterpret_cast<const float4*>(tp + 4);
    float in[8] = {a.x, a.y, a.z, a.w, b.x, b.y, b.z, b.w};
    bf16x8 sv, cv;
#pragma unroll
    for (int e = 0; e < 8; ++e) {
        float s, c;
        __sincosf(in[e], &s, &c);
        sv[e] = (short)f2bf(s);
        cv[e] = (short)f2bf(c);
    }
    const int srow = (row >> 6) * 128 + (row & 63);
    *reinterpret_cast<bf16x8*>(sc + (size_t)srow * N_DIM + kk)        = sv;
    *reinterpret_cast<bf16x8*>(sc + (size_t)(srow + 64) * N_DIM + kk) = cv;
}

// Counted-vmcnt deep-pipelined GEMM (T3+T4+T5):
//   tile 256(sc rows: 128 theta rows x [s;c]) x 256 cols, BK=32 subtiles,
//   4-deep LDS rotation (128 KB), 8 waves (2M x 4N), per-wave C = 128x64.
//   One barrier + counted vmcnt per phase; stage 3 subtiles ahead.
//   Epilogue fully in-register (wave holds Ks in mi 0..3, Kc in mi 4..7 for
//   the SAME theta rows).
__global__ __launch_bounds__(512, 2)
void k_gemm(const unsigned short* __restrict__ sc,
            const float* __restrict__ theta,
            const float* __restrict__ noise,
            const float* __restrict__ omega,
            const unsigned short* __restrict__ Kbf,
            float* __restrict__ out, int rbase) {
    // k-granule-major: [buf][g(4)][row(256)][8 bf16] -> conflict-free b128 reads
    __shared__ unsigned short sA[4][4][256][8];   // 64 KB
    __shared__ unsigned short sB[4][4][256][8];   // 64 KB

    const int tid  = threadIdx.x;
    const int lane = tid & 63;
    const int w    = tid >> 6;      // 0..7
    const int wm   = w >> 2;        // 0..1  (128 sc rows = 64 theta rows x [s;c])
    const int wn   = w & 3;         // 0..3  (64 cols)
    const int lr   = lane & 15;
    const int kq   = lane >> 4;

    // XCD swizzle: 4 col-tiles of one row-panel stay consecutive on one XCD
    const int nwg     = gridDim.x;          // multiple of 8
    const int cpx     = nwg >> 3;
    const int logical = (blockIdx.x & 7) * cpx + (blockIdx.x >> 3);
    const int mt      = logical >> 2;       // row-panel (256 sc rows / 128 theta)
    const int nt      = logical & 3;        // col-tile (256 cols)

    f32x4 acc[8][4];
#pragma unroll
    for (int mi = 0; mi < 8; ++mi)
#pragma unroll
        for (int ni = 0; ni < 4; ++ni)
            acc[mi][ni] = (f32x4){0.f, 0.f, 0.f, 0.f};

    // stage subtile s (k = s*32 .. +32): 4 gload_lds per wave (2 for A, 2 for B)
    auto stage_sub = [&](int s) {
        const int buf = s & 3;
#pragma unroll
        for (int i = 0; i < 2; ++i) {
            const int c  = w * 2 + i;        // 0..15
            const int g  = c >> 2;           // k-granule 0..3
            const int rb = (c & 3) * 64;     // row block
            const unsigned short* srcA =
                sc + (size_t)(mt * 256 + rb + lane) * N_DIM + s * 32 + g * 8;
            gload_lds16(srcA, &sA[buf][g][rb][0]);
            const unsigned short* srcB =
                Kbf + (size_t)(nt * 256 + rb + lane) * N_DIM + s * 32 + g * 8;
            gload_lds16(srcB, &sB[buf][g][rb][0]);
        }
    };

    // prologue: 3 subtiles in flight
    stage_sub(0);
    stage_sub(1);
    stage_sub(2);

    for (int s = 0; s < 32; ++s) {
        // counted wait: subtile s landed; keep s+1, s+2 (8 loads) in flight
        if (s < 30)       asm volatile("s_waitcnt vmcnt(8)" ::: "memory");
        else if (s == 30) asm volatile("s_waitcnt vmcnt(4)" ::: "memory");
        else              asm volatile("s_waitcnt vmcnt(0)" ::: "memory");
        __builtin_amdgcn_s_barrier();   // blockwide: subtile s fully staged

        const int buf = s & 3;
        bf16x8 aF[8], bF[4];
#pragma unroll
        for (int ni = 0; ni < 4; ++ni)
            bF[ni] = *reinterpret_cast<const bf16x8*>(
                &sB[buf][kq][wn * 64 + ni * 16 + lr][0]);
#pragma unroll
        for (int mi = 0; mi < 8; ++mi)
            aF[mi] = *reinterpret_cast<const bf16x8*>(
                &sA[buf][kq][wm * 128 + mi * 16 + lr][0]);

        __builtin_amdgcn_s_setprio(1);
#pragma unroll
        for (int mi = 0; mi < 8; ++mi)
#pragma unroll
            for (int ni = 0; ni < 4; ++ni)
                acc[mi][ni] = __builtin_amdgcn_mfma_f32_16x16x32_bf16(
                    aF[mi], bF[ni], acc[mi][ni], 0, 0, 0);
        __builtin_amdgcn_s_setprio(0);

        // prefetch subtile s+3 into buf (s+3)&3 = (s-1)&3 (readers long done)
        if (s + 3 < 32) stage_sub(s + 3);
    }

    // ---- epilogue: in-register. mi 0..3 = Ks, mi+4 = Kc, same theta rows ----
#pragma unroll
    for (int ni = 0; ni < 4; ++ni) {
        const int colg = nt * 256 + wn * 64 + ni * 16 + lr;
        const float om = omega[colg];
#pragma unroll
        for (int mi = 0; mi < 4; ++mi) {
#pragma unroll
            for (int v = 0; v < 4; ++v) {
                const int rowg = mt * 128 + wm * 64 + mi * 16 + (lane >> 4) * 4 + v;
                const size_t idx = (size_t)(rbase + rowg) * N_DIM + colg;
                const float th = theta[idx];
                float sn, cn;
                __sincosf(th, &sn, &cn);
                const float coup = cn * acc[mi][ni][v] - sn * acc[mi + 4][ni][v];
                out[idx] = th + (om + coup) * DT_C + noise[idx] * NS_SCALE;
            }
        }
    }
}

// ---------------- fallback (R2 kernel, ws too small) ----------------
#define FB_BM 64
#define FB_BN 256
__global__ __launch_bounds__(512, 4)
void k_fused_fb(const float* __restrict__ theta,
                const float* __restrict__ noise,
                const float* __restrict__ omega,
                const unsigned short* __restrict__ Kbf,
                float* __restrict__ out) {
    __shared__ unsigned short sA[2][2][4][FB_BM][8];
    __shared__ unsigned short sB[2][4][FB_BN][8];

    const int tid  = threadIdx.x;
    const int lane = tid & 63;
    const int w    = tid >> 6;
    const int wm   = w >> 2;
    const int wn   = w & 3;

    const int nwg     = gridDim.x;
    const int cpx     = nwg >> 3;
    const int logical = (blockIdx.x & 7) * cpx + (blockIdx.x >> 3);
    const int mt      = logical >> 2;
    const int nt      = logical & 3;
    const int row0    = mt * FB_BM;
    const int col0    = nt * FB_BN;

    const int q = tid >> 7;
    const int r = (tid >> 1) & 63;
    const int h = tid & 1;
    const int rb  = (w & 3) * 64;
    const int it0 = (w >> 2) * 2;

    f32x4 accS[2][4], accC[2][4];
#pragma unroll
    for (int mi = 0; mi < 2; ++mi)
#pragma unroll
        for (int ni = 0; ni < 4; ++ni) {
            accS[mi][ni] = (f32x4){0.f, 0.f, 0.f, 0.f};
            accC[mi][ni] = (f32x4){0.f, 0.f, 0.f, 0.f};
        }

    auto stage = [&](int buf, int kt) {
#pragma unroll
        for (int j = 0; j < 2; ++j) {
            const int it = it0 + j;
            const unsigned short* src =
                Kbf + (size_t)(col0 + rb + lane) * N_DIM + kt * 32 + it * 8;
            gload_lds16(src, &sB[buf][it][rb][0]);
        }
        const float* gp = theta + (size_t)(row0 + r) * N_DIM + kt * 32 + q * 8 + h * 4;
        float4 v = *reinterpret_cast<const float4*>(gp);
        ushort4 sv, cv;
        {
            float s0, c0, s1, c1, s2, c2, s3, c3;
            __sincosf(v.x, &s0, &c0);
            __sincosf(v.y, &s1, &c1);
            __sincosf(v.z, &s2, &c2);
            __sincosf(v.w, &s3, &c3);
            sv.x = f2bf(s0); sv.y = f2bf(s1); sv.z = f2bf(s2); sv.w = f2bf(s3);
            cv.x = f2bf(c0); cv.y = f2bf(c1); cv.z = f2bf(c2); cv.w = f2bf(c3);
        }
        *reinterpret_cast<ushort4*>(&sA[buf][0][q][r][h * 4]) = sv;
        *reinterpret_cast<ushort4*>(&sA[buf][1][q][r][h * 4]) = cv;
    };

    auto compute = [&](int buf) {
        const int kq2 = lane >> 4;
        const int lr2 = lane & 15;
        bf16x8 aS[2], aC[2];
#pragma unroll
        for (int mi = 0; mi < 2; ++mi) {
            aS[mi] = *reinterpret_cast<const bf16x8*>(&sA[buf][0][kq2][wm * 32 + mi * 16 + lr2][0]);
            aC[mi] = *reinterpret_cast<const bf16x8*>(&sA[buf][1][kq2][wm * 32 + mi * 16 + lr2][0]);
        }
#pragma unroll
        for (int ni = 0; ni < 4; ++ni) {
            bf16x8 bF = *reinterpret_cast<const bf16x8*>(&sB[buf][kq2][wn * 64 + ni * 16 + lr2][0]);
#pragma unroll
            for (int mi = 0; mi < 2; ++mi) {
                accS[mi][ni] = __builtin_amdgcn_mfma_f32_16x16x32_bf16(aS[mi], bF, accS[mi][ni], 0, 0, 0);
                accC[mi][ni] = __builtin_amdgcn_mfma_f32_16x16x32_bf16(aC[mi], bF, accC[mi][ni], 0, 0, 0);
            }
        }
    };

    stage(0, 0);
    __syncthreads();
    int cur = 0;
    for (int kt = 0; kt < 32; ++kt) {
        if (kt + 1 < 32) stage(cur ^ 1, kt + 1);
        compute(cur);
        __syncthreads();
        cur ^= 1;
    }

#pragma unroll
    for (int mi = 0; mi < 2; ++mi) {
#pragma unroll
        for (int ni = 0; ni < 4; ++ni) {
            const int colg = col0 + wn * 64 + ni * 16 + (lane & 15);
            const float om = omega[colg];
#pragma unroll
            for (int v = 0; v < 4; ++v) {
                const int rowg = row0 + wm * 32 + mi * 16 + (lane >> 4) * 4 + v;
                const size_t idx = (size_t)rowg * N_DIM + colg;
                const float th = theta[idx];
                float sn, cn;
                __sincosf(th, &sn, &cn);
                const float coup = cn * accS[mi][ni][v] - sn * accC[mi][ni][v];
                out[idx] = th + (om + coup) * DT_C + noise[idx] * NS_SCALE;
            }
        }
    }
}

extern "C" void kernel_launch(void* const* d_in, const int* in_sizes, int n_in,
                              void* d_out, int out_size, void* d_ws, size_t ws_size,
                              hipStream_t stream) {
    const float* theta = (const float*)d_in[0];
    const float* noise = (const float*)d_in[1];
    const float* omega = (const float*)d_in[2];
    const float* K     = (const float*)d_in[3];
    float* out = (float*)d_out;

    unsigned short* Kbf = (unsigned short*)d_ws;   // 2 MB @ offset 0
    k_convK<<<(N_DIM * N_DIM) / (256 * 4), 256, 0, stream>>>(K, Kbf);

    // Chunk R rows: sc chunk needs R*4096 bytes after a 4MB reserve.
    size_t avail = ws_size > (size_t)(4 << 20) ? ws_size - (size_t)(4 << 20) : 0;
    int R = 0;
    for (int cand = 65536; cand >= 1024; cand >>= 1)
        if ((size_t)cand * 4096 <= avail) { R = cand; break; }

    if (R > 0) {
        unsigned short* sc = (unsigned short*)((char*)d_ws + (4 << 20));
        const int nch = B_DIM / R;
        for (int ch = 0; ch < nch; ++ch) {
            const int rbase = ch * R;
            k_prep<<<R / 2, 256, 0, stream>>>(theta, sc, rbase);
            k_gemm<<<(R / 128) * 4, 512, 0, stream>>>(sc, theta, noise, omega, Kbf, out, rbase);
        }
    } else {
        k_fused_fb<<<(B_DIM / FB_BM) * (N_DIM / FB_BN), 512, 0, stream>>>(
            theta, noise, omega, Kbf, out);
    }
}